// Round 2
// baseline (950.685 us; speedup 1.0000x reference)
//
#include <hip/hip_runtime.h>
#include <stdint.h>

#define BDIM 16384
#define HDIM 1024
#define BHSZ (BDIM * HDIM)

typedef unsigned short u16;
typedef __attribute__((ext_vector_type(8))) short short8;   // 8 bf16 (4 VGPRs) MFMA A/B frag
typedef __attribute__((ext_vector_type(4))) float floatx4;  // MFMA C/D frag

typedef __attribute__((address_space(1))) const void gvoid;
typedef __attribute__((address_space(3))) void lvoid;

__device__ __forceinline__ float bf2f(u16 u) {
  union { uint32_t i; float f; } c; c.i = ((uint32_t)u) << 16; return c.f;
}
__device__ __forceinline__ u16 f2bf(float f) {
  union { float f; uint32_t i; } c; c.f = f;
  uint32_t r = (c.i + 0x7fffu + ((c.i >> 16) & 1u)) >> 16;
  return (u16)r;
}
__device__ __forceinline__ uint4 pack8(const float* f) {
  uint4 v;
  v.x = (uint32_t)f2bf(f[0]) | ((uint32_t)f2bf(f[1]) << 16);
  v.y = (uint32_t)f2bf(f[2]) | ((uint32_t)f2bf(f[3]) << 16);
  v.z = (uint32_t)f2bf(f[4]) | ((uint32_t)f2bf(f[5]) << 16);
  v.w = (uint32_t)f2bf(f[6]) | ((uint32_t)f2bf(f[7]) << 16);
  return v;
}

// ---------------------------------------------------------------------------
// fp32 -> bf16 convert (weights)
// ---------------------------------------------------------------------------
__global__ __launch_bounds__(256) void f2b_kernel(
    const float* __restrict__ in, u16* __restrict__ out) {
  const int idx = (blockIdx.x * 256 + threadIdx.x) * 8;
  float4 v0 = *(const float4*)(in + idx);
  float4 v1 = *(const float4*)(in + idx + 4);
  float f[8] = {v0.x, v0.y, v0.z, v0.w, v1.x, v1.y, v1.z, v1.w};
  *(uint4*)(out + idx) = pack8(f);
}

// ---------------------------------------------------------------------------
// mix: xmix(bf16) = x*tm + alpha*(1-tm); optional fp32 verbatim x copy
// ---------------------------------------------------------------------------
__global__ __launch_bounds__(256) void mix_kernel(
    const float* __restrict__ x, const float* __restrict__ alpha,
    const float* __restrict__ tm, u16* __restrict__ xmix,
    float* __restrict__ xcopy) {
  const int idx = (blockIdx.x * 256 + threadIdx.x) * 8;
  const int h = idx & (HDIM - 1);
  float4 x0 = *(const float4*)(x + idx);
  float4 x1 = *(const float4*)(x + idx + 4);
  float4 a0 = *(const float4*)(alpha + idx);
  float4 a1 = *(const float4*)(alpha + idx + 4);
  float4 t0 = *(const float4*)(tm + h);
  float4 t1 = *(const float4*)(tm + h + 4);
  float xf[8] = {x0.x, x0.y, x0.z, x0.w, x1.x, x1.y, x1.z, x1.w};
  float af[8] = {a0.x, a0.y, a0.z, a0.w, a1.x, a1.y, a1.z, a1.w};
  float tf[8] = {t0.x, t0.y, t0.z, t0.w, t1.x, t1.y, t1.z, t1.w};
  float of[8];
#pragma unroll
  for (int j = 0; j < 8; ++j) of[j] = xf[j] * tf[j] + af[j] * (1.0f - tf[j]);
  *(uint4*)(xmix + idx) = pack8(of);
  if (xcopy) {
    *(float4*)(xcopy + idx) = x0;
    *(float4*)(xcopy + idx + 4) = x1;
  }
}

// ---------------------------------------------------------------------------
// GEMM core: acc[4][4] = A[M,K](bf16) @ W[N,K]^T(bf16) for one 128x128 tile
// (m97 structure: BK=32, global_load_lds width=16, 4 waves 2x2, 4x4 MFMAs)
// ---------------------------------------------------------------------------
__device__ __forceinline__ void gemm_core(
    const u16* __restrict__ A, const u16* __restrict__ W, int K,
    int mBase, int nBase, u16* As, u16* Bs, floatx4 acc[4][4]) {
  const int tid = threadIdx.x;
  const int lane = tid & 63;
  const int wave = tid >> 6;
  const int wm = (wave >> 1) * 64;
  const int wn = (wave & 1) * 64;
  const int lm = lane & 15;
  const int lk = (lane >> 4) * 8;

#pragma unroll
  for (int i = 0; i < 4; ++i)
#pragma unroll
    for (int j = 0; j < 4; ++j) acc[i][j] = (floatx4){0.f, 0.f, 0.f, 0.f};

  for (int k0 = 0; k0 < K; k0 += 32) {
#pragma unroll
    for (int p = 0; p < 2; ++p) {
      const int g = tid + p * 256;               // 0..511
      const int row = g >> 2;                    // 0..127
      const int col = (g & 3) * 8;               // 0/8/16/24
      const u16* ga = A + (size_t)(mBase + row) * K + (k0 + col);
      const u16* gb = W + (size_t)(nBase + row) * K + (k0 + col);
      __builtin_amdgcn_global_load_lds((gvoid*)ga, (lvoid*)(As + g * 8), 16, 0, 0);
      __builtin_amdgcn_global_load_lds((gvoid*)gb, (lvoid*)(Bs + g * 8), 16, 0, 0);
    }
    __syncthreads();

    short8 a[4], b[4];
#pragma unroll
    for (int i = 0; i < 4; ++i)
      a[i] = *(const short8*)(As + (wm + i * 16 + lm) * 32 + lk);
#pragma unroll
    for (int i = 0; i < 4; ++i)
      b[i] = *(const short8*)(Bs + (wn + i * 16 + lm) * 32 + lk);
#pragma unroll
    for (int mi = 0; mi < 4; ++mi)
#pragma unroll
      for (int ni = 0; ni < 4; ++ni)
        acc[mi][ni] = __builtin_amdgcn_mfma_f32_16x16x32_bf16(
            a[mi], b[ni], acc[mi][ni], 0, 0, 0);
    __syncthreads();
  }
}

// C/D layout [m89-verified]: col = lane&15, row = (lane>>4)*4 + reg

// GEMM writing bf16 C (for k, v)
__global__ __launch_bounds__(256) void gemm_bf16out(
    const u16* __restrict__ A, const u16* __restrict__ W,
    u16* __restrict__ C, int K, int N) {
  __shared__ u16 As[128 * 32];
  __shared__ u16 Bs[128 * 32];
  floatx4 acc[4][4];
  const int mBase = blockIdx.y * 128;
  const int nBase = blockIdx.x * 128;
  gemm_core(A, W, K, mBase, nBase, As, Bs, acc);
  const int lane = threadIdx.x & 63;
  const int wave = threadIdx.x >> 6;
  const int wm = (wave >> 1) * 64, wn = (wave & 1) * 64;
  const int lm = lane & 15, rBase = (lane >> 4) * 4;
#pragma unroll
  for (int mi = 0; mi < 4; ++mi)
#pragma unroll
    for (int ni = 0; ni < 4; ++ni) {
      const int gn = nBase + wn + ni * 16 + lm;
#pragma unroll
      for (int r = 0; r < 4; ++r) {
        const int gm = mBase + wm + mi * 16 + rBase + r;
        C[(size_t)gm * N + gn] = f2bf(acc[mi][ni][r]);
      }
    }
}

// GEMM writing fp32 C (final out = (r*wkv) @ Wo^T)
__global__ __launch_bounds__(256) void gemm_f32out(
    const u16* __restrict__ A, const u16* __restrict__ W,
    float* __restrict__ C, int K, int N) {
  __shared__ u16 As[128 * 32];
  __shared__ u16 Bs[128 * 32];
  floatx4 acc[4][4];
  const int mBase = blockIdx.y * 128;
  const int nBase = blockIdx.x * 128;
  gemm_core(A, W, K, mBase, nBase, As, Bs, acc);
  const int lane = threadIdx.x & 63;
  const int wave = threadIdx.x >> 6;
  const int wm = (wave >> 1) * 64, wn = (wave & 1) * 64;
  const int lm = lane & 15, rBase = (lane >> 4) * 4;
#pragma unroll
  for (int mi = 0; mi < 4; ++mi)
#pragma unroll
    for (int ni = 0; ni < 4; ++ni) {
      const int gn = nBase + wn + ni * 16 + lm;
#pragma unroll
      for (int r = 0; r < 4; ++r) {
        const int gm = mBase + wm + mi * 16 + rBase + r;
        C[(size_t)gm * N + gn] = acc[mi][ni][r];
      }
    }
}

// r-GEMM with fused WKV epilogue.
//   acc = xr @ Wr^T (pre-sigmoid r). Per element (gm,gn):
//   reads k,v (bf16 ws), aa,bb,pp (fp32 in), tdec,tfirst (fp32 in);
//   writes rwkv = sigmoid(acc)*wkv OVER kbuf (each element: one reader=writer),
//   and next_aa/next_bb/qq2 (fp32 outputs).
__global__ __launch_bounds__(256) void gemm_r_wkv(
    const u16* __restrict__ A, const u16* __restrict__ W,
    u16* __restrict__ kbuf, const u16* __restrict__ vbuf,
    const float* __restrict__ aa, const float* __restrict__ bb,
    const float* __restrict__ pp, const float* __restrict__ tdec,
    const float* __restrict__ tfirst, float* __restrict__ naa,
    float* __restrict__ nbb, float* __restrict__ qq2, int K, int N) {
  __shared__ u16 As[128 * 32];
  __shared__ u16 Bs[128 * 32];
  floatx4 acc[4][4];
  const int mBase = blockIdx.y * 128;
  const int nBase = blockIdx.x * 128;
  gemm_core(A, W, K, mBase, nBase, As, Bs, acc);
  const int lane = threadIdx.x & 63;
  const int wave = threadIdx.x >> 6;
  const int wm = (wave >> 1) * 64, wn = (wave & 1) * 64;
  const int lm = lane & 15, rBase = (lane >> 4) * 4;
#pragma unroll
  for (int mi = 0; mi < 4; ++mi)
#pragma unroll
    for (int ni = 0; ni < 4; ++ni) {
      const int gn = nBase + wn + ni * 16 + lm;
      const float td = tdec[gn];
      const float tf = tfirst[gn];
#pragma unroll
      for (int r = 0; r < 4; ++r) {
        const int gm = mBase + wm + mi * 16 + rBase + r;
        const size_t off = (size_t)gm * N + gn;
        const float kk = bf2f(kbuf[off]);
        const float vv = bf2f(vbuf[off]);
        const float A_ = aa[off];
        const float B_ = bb[off];
        const float P_ = pp[off];
        const float rr = 1.0f / (1.0f + __expf(-acc[mi][ni][r]));
        const float ww = tf + kk;
        const float qq = fmaxf(P_, ww);
        const float e1 = __expf(P_ - qq);
        const float e2 = __expf(ww - qq);
        const float wkv = (e1 * A_ + e2 * vv) / (e1 * B_ + e2);
        kbuf[off] = f2bf(rr * wkv);
        const float ww2 = P_ + td;
        const float q = fmaxf(ww2, kk);
        const float e1b = __expf(ww2 - q);
        const float e2b = __expf(kk - q);
        naa[off] = e1b * A_ + e2b * vv;
        nbb[off] = e1b * B_ + e2b;
        qq2[off] = q;
      }
    }
}

// ---------------------------------------------------------------------------
extern "C" void kernel_launch(void* const* d_in, const int* in_sizes, int n_in,
                              void* d_out, int out_size, void* d_ws, size_t ws_size,
                              hipStream_t stream) {
  const float* x      = (const float*)d_in[0];
  const float* alpha  = (const float*)d_in[1];
  const float* aa     = (const float*)d_in[2];
  const float* bb     = (const float*)d_in[3];
  const float* pp     = (const float*)d_in[4];
  const float* tdec   = (const float*)d_in[5];
  const float* tfirst = (const float*)d_in[6];
  const float* tmk    = (const float*)d_in[7];
  const float* tmv    = (const float*)d_in[8];
  const float* tmr    = (const float*)d_in[9];
  const float* Wk     = (const float*)d_in[10];
  const float* Wv     = (const float*)d_in[11];
  const float* Wr     = (const float*)d_in[12];
  const float* Wo     = (const float*)d_in[13];

  float* out  = (float*)d_out;              // output 0: out
  float* outx = out + (size_t)BHSZ;         // output 1: x (verbatim copy)
  float* naa  = out + 2 * (size_t)BHSZ;     // output 2: next_aa
  float* nbb  = out + 3 * (size_t)BHSZ;     // output 3: next_bb
  float* qq2  = out + 4 * (size_t)BHSZ;     // output 4: qq2

  // ws (bf16 scratch, ~98 MB): mixbuf | kbuf | vbuf | wbuf(2 MB, reused 4x)
  u16* mixbuf = (u16*)d_ws;
  u16* kbuf   = mixbuf + (size_t)BHSZ;
  u16* vbuf   = mixbuf + 2 * (size_t)BHSZ;
  u16* wbuf   = mixbuf + 3 * (size_t)BHSZ;

  const dim3 gEW(BHSZ / (256 * 8));
  const dim3 gW(HDIM * HDIM / (256 * 8));
  const dim3 gG(HDIM / 128, BDIM / 128);

  // k = mix_k(x,alpha) @ Wk^T
  mix_kernel<<<gEW, 256, 0, stream>>>(x, alpha, tmk, mixbuf, outx);
  f2b_kernel<<<gW, 256, 0, stream>>>(Wk, wbuf);
  gemm_bf16out<<<gG, 256, 0, stream>>>(mixbuf, wbuf, kbuf, HDIM, HDIM);
  // v = mix_v(x,alpha) @ Wv^T
  mix_kernel<<<gEW, 256, 0, stream>>>(x, alpha, tmv, mixbuf, nullptr);
  f2b_kernel<<<gW, 256, 0, stream>>>(Wv, wbuf);
  gemm_bf16out<<<gG, 256, 0, stream>>>(mixbuf, wbuf, vbuf, HDIM, HDIM);
  // r-GEMM + fused WKV: kbuf <- r*wkv; naa/nbb/qq2 written
  mix_kernel<<<gEW, 256, 0, stream>>>(x, alpha, tmr, mixbuf, nullptr);
  f2b_kernel<<<gW, 256, 0, stream>>>(Wr, wbuf);
  gemm_r_wkv<<<gG, 256, 0, stream>>>(mixbuf, wbuf, kbuf, vbuf, aa, bb, pp,
                                     tdec, tfirst, naa, nbb, qq2, HDIM, HDIM);
  // out = (r*wkv) @ Wo^T
  f2b_kernel<<<gW, 256, 0, stream>>>(Wo, wbuf);
  gemm_f32out<<<gG, 256, 0, stream>>>(kbuf, wbuf, out, HDIM, HDIM);
}